// Round 7
// baseline (14156.235 us; speedup 1.0000x reference)
//
#include <hip/hip_runtime.h>

// GeodesicStateBlock: GRU-style scan (B=16,S=2048,D=512) + LayerNorm.
// Identity: deformed = points + (states - points) = states, so out = LN(states).
//
// Round-10 = round-9's token-in-dword protocol, exchanged through ONE XCD's
// L2 when (and only when) hardware-verified possible.
//  - Election (deadlock-free by construction): 128 blocks each publish their
//    XCC_ID to ids[bid] (sc0 sc1 = LLC-coherent) unconditionally at entry,
//    then spin until all 128 slots are non-zero (terminates: every slot is
//    written unconditionally; 128 blocks <= 256 CUs are all resident).
//    Winner XCD = first with >=16 blocks (pigeonhole: 128/8 guarantees one);
//    worker ranks = position among winner-group by blockIdx. Computed from
//    identical data in every block -- no atomics, no CAS, no races.
//  - Coherence probe (bounded, no-hang): 16 candidates ping-pong 4 rounds on
//    ONE sc0-only word (writers = ranks 0..3). Observing the same address
//    UPDATE repeatedly is only possible when reader and writer share a
//    physical L2 (a non-coherent cached copy pins the first value ->
//    bounded spin times out -> fail). Results are published on an
//    LLC-coherent consensus array; all 16 agree on fast vs fallback.
//    Fallback = round-9's proven LLC path (sc0 sc1).
//  - Scan (both paths): h / r*h as packed dwords (token<<16)|f16_bits;
//    aligned 4B accesses are single-copy atomic => self-validating; the
//    consumer's validation IS the synchronization. Cooperative staging
//    (wave w owns fragments 4w..4w+3) into double-buffered LDS; 2
//    __syncthreads per step. WAR/deadlock chain as proven in rounds 8/9.
//  - Why: both round-5 and round-9 floor at ~5.5-6us/step = ~4 Infinity
//    Cache RTs (memory-attached, ~900cy). Same-XCD L2 RT ~200cy.

typedef _Float16 half8 __attribute__((ext_vector_type(8)));
typedef _Float16 half4 __attribute__((ext_vector_type(4)));
typedef float floatx4 __attribute__((ext_vector_type(4)));
typedef int int4v __attribute__((ext_vector_type(4)));

#define NBLK 16
#define NGRID 128
#define TPB 256
#define S_LEN 2048

// ws layout (bytes)
#define SZ_WPK (96ull * 16 * 64 * 8 * 2)  // 1,572,864 (96 tiles x 16 KB)
#define OFF_WHPK 0ull
#define OFF_WXPK (OFF_WHPK + SZ_WPK)
#define OFF_HBUF (OFF_WXPK + SZ_WPK)    // 32 KB: h2[16][512] dwords (zeroed)
#define OFF_RH (OFF_HBUF + 32768ull)    // 32 KB: rh2[16][512] dwords (zeroed)
#define OFF_CNT (OFF_RH + 32768ull)     // 16 KB (zeroed):
                                        //  [0..127]   election ids (0x100|xcd)
                                        //  [160..175] probe consensus (1/2)
                                        //  [192]      probe ping-pong word
#define OFF_XGT (OFF_CNT + 16384ull)    // 2048*96*256*2 = 100,663,296 B

__device__ __forceinline__ float sigmoid_f(float x) {
  return 1.f / (1.f + __expf(-x));
}
__device__ __forceinline__ float tanh_f(float x) {
  x = fminf(15.f, fmaxf(-15.f, x));
  float e = __expf(2.f * x);
  return (e - 1.f) / (e + 1.f);
}

// ---- scope-templated memory ops: SC1=1 LLC-coherent, SC1=0 XCD-L2 ----
template <int SC1>
__device__ __forceinline__ void ld8_t(const unsigned* p, int4v (&d)[8]) {
  if constexpr (SC1) {
    asm volatile(
        "global_load_dwordx4 %0, %8, off sc0 sc1\n\t"
        "global_load_dwordx4 %1, %8, off offset:16 sc0 sc1\n\t"
        "global_load_dwordx4 %2, %8, off offset:128 sc0 sc1\n\t"
        "global_load_dwordx4 %3, %8, off offset:144 sc0 sc1\n\t"
        "global_load_dwordx4 %4, %8, off offset:256 sc0 sc1\n\t"
        "global_load_dwordx4 %5, %8, off offset:272 sc0 sc1\n\t"
        "global_load_dwordx4 %6, %8, off offset:384 sc0 sc1\n\t"
        "global_load_dwordx4 %7, %8, off offset:400 sc0 sc1\n\t"
        "s_waitcnt vmcnt(0)"
        : "=&v"(d[0]), "=&v"(d[1]), "=&v"(d[2]), "=&v"(d[3]), "=&v"(d[4]),
          "=&v"(d[5]), "=&v"(d[6]), "=&v"(d[7])
        : "v"(p)
        : "memory");
  } else {
    asm volatile(
        "global_load_dwordx4 %0, %8, off sc0\n\t"
        "global_load_dwordx4 %1, %8, off offset:16 sc0\n\t"
        "global_load_dwordx4 %2, %8, off offset:128 sc0\n\t"
        "global_load_dwordx4 %3, %8, off offset:144 sc0\n\t"
        "global_load_dwordx4 %4, %8, off offset:256 sc0\n\t"
        "global_load_dwordx4 %5, %8, off offset:272 sc0\n\t"
        "global_load_dwordx4 %6, %8, off offset:384 sc0\n\t"
        "global_load_dwordx4 %7, %8, off offset:400 sc0\n\t"
        "s_waitcnt vmcnt(0)"
        : "=&v"(d[0]), "=&v"(d[1]), "=&v"(d[2]), "=&v"(d[3]), "=&v"(d[4]),
          "=&v"(d[5]), "=&v"(d[6]), "=&v"(d[7])
        : "v"(p)
        : "memory");
  }
}
template <int SC1>
__device__ __forceinline__ void st_dw_t(unsigned* p, unsigned v) {
  if constexpr (SC1)
    asm volatile("global_store_dword %0, %1, off sc0 sc1" ::"v"(p), "v"(v)
                 : "memory");
  else
    asm volatile("global_store_dword %0, %1, off sc0" ::"v"(p), "v"(v)
                 : "memory");
}
template <int SC1>
__device__ __forceinline__ unsigned ld_dw_t(const unsigned* p) {
  unsigned v;
  if constexpr (SC1)
    asm volatile("global_load_dword %0, %1, off sc0 sc1\n\ts_waitcnt vmcnt(0)"
                 : "=v"(v)
                 : "v"(p)
                 : "memory");
  else
    asm volatile("global_load_dword %0, %1, off sc0\n\ts_waitcnt vmcnt(0)"
                 : "=v"(v)
                 : "v"(p)
                 : "memory");
  return v;
}
// pack low16 of (p0,p1) -> one dword (p0 low, p1 high)
__device__ __forceinline__ unsigned pk2(unsigned p1, unsigned p0) {
  return __builtin_amdgcn_perm(p1, p0, 0x05040100u);
}

// Validated cooperative stage: spin until this wave's 4 fragments all carry
// `tokhi`, then unpack payloads to LDS (stride 64 int4v between fragments).
template <int SC1>
__device__ __forceinline__ void stage_val_t(const unsigned* p, unsigned tokhi,
                                            int4v* lds_dst) {
  int4v d[8];
  for (;;) {
    ld8_t<SC1>(p, d);
    unsigned acc = 0;
#pragma unroll
    for (int u = 0; u < 8; ++u)
#pragma unroll
      for (int c = 0; c < 4; ++c) acc |= ((unsigned)d[u][c]) ^ tokhi;
    if (__all((int)((acc >> 16) == 0u))) break;
    if constexpr (SC1) __builtin_amdgcn_s_sleep(2);  // cap LLC retry pressure
  }
#pragma unroll
  for (int u = 0; u < 4; ++u) {
    int4v f;
    f[0] = (int)pk2((unsigned)d[2 * u][1], (unsigned)d[2 * u][0]);
    f[1] = (int)pk2((unsigned)d[2 * u][3], (unsigned)d[2 * u][2]);
    f[2] = (int)pk2((unsigned)d[2 * u + 1][1], (unsigned)d[2 * u + 1][0]);
    f[3] = (int)pk2((unsigned)d[2 * u + 1][3], (unsigned)d[2 * u + 1][2]);
    lds_dst[u * 64] = f;
  }
}

// ---- pack weights into MFMA B-fragment order ----
// Whpk/Wxpk: [96 tiles][16 kc][64 lanes][8 f16]; tiles 0..63 gate, 64..95 cand.
// B-frag: lane holds B[k = kc*32 + (lane>>4)*8 + jj][n = lane&15].
__global__ void pack_kernel(const float* __restrict__ Wg,
                            const float* __restrict__ Wc,
                            _Float16* __restrict__ Whpk,
                            _Float16* __restrict__ Wxpk) {
  int unit = blockIdx.x * 4 + (threadIdx.x >> 6);  // 0..3071
  int lane = threadIdx.x & 63;
  int set = (unit >= 1536) ? 1 : 0;  // 0: h-part (rows 512+), 1: x-part
  int rem = unit - set * 1536;
  int tile = rem >> 4, kc = rem & 15;
  int kb = kc * 32 + ((lane >> 4) << 3);
  int n = lane & 15;
  int row0 = set ? 0 : 512;
  half8 w;
  if (tile < 64) {
    int col = tile * 16 + n;
#pragma unroll
    for (int jj = 0; jj < 8; ++jj)
      w[jj] = (_Float16)Wg[(size_t)(row0 + kb + jj) * 1024 + col];
  } else {
    int col = (tile - 64) * 16 + n;
#pragma unroll
    for (int jj = 0; jj < 8; ++jj)
      w[jj] = (_Float16)Wc[(size_t)(row0 + kb + jj) * 512 + col];
  }
  _Float16* dst = set ? Wxpk : Whpk;
  *(half8*)(dst + ((size_t)rem * 64 + lane) * 8) = w;
}

// ---- XGT = points @ W_x + bias, all steps; layout [t][tile][c16][b16] ----
__global__ __launch_bounds__(TPB) void xgemm_kernel(
    const float* __restrict__ points, const float* __restrict__ b_gate,
    const float* __restrict__ b_cand, const _Float16* __restrict__ Wxpk,
    _Float16* __restrict__ xgt) {
  __shared__ _Float16 x_lds[16][520];
  const int tid = threadIdx.x;
  const int wave = tid >> 6, lane = tid & 63;
  const int ln15 = lane & 15, q = lane >> 4;
  const int t = blockIdx.x;
  const int m = tid & 15, ch = tid >> 4;

  // stage x_t (f32 -> f16)
  const float* xp = points + ((size_t)m * S_LEN + t) * 512 + ch * 32;
#pragma unroll
  for (int u = 0; u < 4; ++u) {
    float4 f0 = ((const float4*)xp)[2 * u];
    float4 f1 = ((const float4*)xp)[2 * u + 1];
    half8 hv;
    hv[0] = (_Float16)f0.x; hv[1] = (_Float16)f0.y;
    hv[2] = (_Float16)f0.z; hv[3] = (_Float16)f0.w;
    hv[4] = (_Float16)f1.x; hv[5] = (_Float16)f1.y;
    hv[6] = (_Float16)f1.z; hv[7] = (_Float16)f1.w;
    *(half8*)&x_lds[m][ch * 32 + u * 8] = hv;
  }
  __syncthreads();

  for (int tile = wave; tile < 96; tile += 4) {
    const _Float16* W = Wxpk + (size_t)tile * 8192;
    floatx4 a0 = {0.f, 0.f, 0.f, 0.f}, a1 = {0.f, 0.f, 0.f, 0.f};
#pragma unroll
    for (int kc = 0; kc < 16; kc += 2) {
      a0 = __builtin_amdgcn_mfma_f32_16x16x32_f16(
          *(const half8*)&x_lds[ln15][kc * 32 + q * 8],
          *(const half8*)(W + ((size_t)kc * 64 + lane) * 8), a0, 0, 0, 0);
      a1 = __builtin_amdgcn_mfma_f32_16x16x32_f16(
          *(const half8*)&x_lds[ln15][(kc + 1) * 32 + q * 8],
          *(const half8*)(W + ((size_t)(kc + 1) * 64 + lane) * 8), a1, 0, 0, 0);
    }
    float bias = (tile < 64) ? b_gate[tile * 16 + ln15]
                             : b_cand[(tile - 64) * 16 + ln15];
    half4 o;
#pragma unroll
    for (int i = 0; i < 4; ++i) o[i] = (_Float16)(a0[i] + a1[i] + bias);
    *(half4*)(xgt + (((size_t)t * 96 + tile) * 16 + ln15) * 16 + q * 4) = o;
  }
}

// ---- the scan loop, templated on exchange scope ----
template <int SC1>
__device__ void scan_loop(int j, int wave, int lane,
                          const _Float16* __restrict__ Whpk,
                          const _Float16* __restrict__ xgt,
                          unsigned* __restrict__ h2,
                          unsigned* __restrict__ rh2, float* __restrict__ out,
                          int4v (*hsh)[1024], float (*z_lds)[36]) {
  const int ln15 = lane & 15, q = lane >> 4;

  const int twA = (wave < 2) ? (2 * j + wave) : (32 + 2 * j + (wave - 2));
  const int twB = 64 + 2 * j + (wave & 1);
  const int colA = 32 * j + 16 * (wave & 1) + ln15;

  half8 wA[16], wB[16];
  {
    const _Float16* sA = Whpk + (size_t)twA * 8192 + lane * 8;
#pragma unroll
    for (int kc = 0; kc < 16; ++kc) wA[kc] = *(const half8*)(sA + kc * 512);
  }
  if (wave < 2) {
    const _Float16* sB = Whpk + (size_t)twB * 8192 + lane * 8;
#pragma unroll
    for (int kc = 0; kc < 16; ++kc) wB[kc] = *(const half8*)(sB + kc * 512);
  }

  const unsigned* h2rd = h2 + ln15 * 512 + q * 8 + wave * 128;
  const unsigned* rh2rd = rh2 + ln15 * 512 + q * 8 + wave * 128;
  unsigned* rh2wr = rh2 + (q * 4) * 512 + colA;  // + i*512
  unsigned* h2wr = h2 + (q * 4) * 512 + colA;    // + i*512
  int4v* ldsA = &hsh[0][(4 * wave) * 64 + lane];
  int4v* ldsB = &hsh[1][(4 * wave) * 64 + lane];

  const _Float16* xga_p = xgt + ((size_t)twA * 16 + ln15) * 16 + q * 4;
  const _Float16* xcb_p = xgt + ((size_t)twB * 16 + ln15) * 16 + q * 4;
  half4 xga = *(const half4*)xga_p;
  half4 xcb = {0, 0, 0, 0};
  if (wave < 2) xcb = *(const half4*)xcb_p;

  float hreg[4] = {0.f, 0.f, 0.f, 0.f};

  for (int t = 0; t < S_LEN; ++t) {
    const size_t pn = (size_t)((t + 1 < S_LEN) ? t + 1 : t) * 24576;
    const unsigned tok1 = (unsigned)t + 1u;
    const unsigned tokhi1 = tok1 << 16;

    // phase A: co-op validated h@t stage (token == t)
    stage_val_t<SC1>(h2rd, ((unsigned)t) << 16, ldsA);
    __syncthreads();

    floatx4 a0 = {0.f, 0.f, 0.f, 0.f}, a1 = {0.f, 0.f, 0.f, 0.f};
#pragma unroll
    for (int kc = 0; kc < 16; kc += 2) {
      a0 = __builtin_amdgcn_mfma_f32_16x16x32_f16(
          *(const half8*)&hsh[0][kc * 64 + lane], wA[kc], a0, 0, 0, 0);
      a1 = __builtin_amdgcn_mfma_f32_16x16x32_f16(
          *(const half8*)&hsh[0][(kc + 1) * 64 + lane], wA[kc + 1], a1, 0, 0,
          0);
    }
    if (wave < 2) {
      half4 xga_nx = *(const half4*)(xga_p + pn);
#pragma unroll
      for (int i = 0; i < 4; ++i) {
        float r = sigmoid_f(a0[i] + a1[i] + (float)xga[i]);
        unsigned hv = (unsigned)__builtin_bit_cast(unsigned short,
                                                   (_Float16)(r * hreg[i]));
        st_dw_t<SC1>(rh2wr + i * 512, tokhi1 | hv);
      }
      xga = xga_nx;
    } else {
#pragma unroll
      for (int i = 0; i < 4; ++i)
        z_lds[q * 4 + i][16 * (wave - 2) + ln15] =
            sigmoid_f(a0[i] + a1[i] + (float)xga[i]);
      xga = *(const half4*)(xga_p + pn);
    }

    // phase B: co-op validated rh@t+1 stage (token == t+1)
    stage_val_t<SC1>(rh2rd, tokhi1, ldsB);
    __syncthreads();

    if (wave < 2) {
      floatx4 b0 = {0.f, 0.f, 0.f, 0.f}, b1 = {0.f, 0.f, 0.f, 0.f};
#pragma unroll
      for (int kc = 0; kc < 16; kc += 2) {
        b0 = __builtin_amdgcn_mfma_f32_16x16x32_f16(
            *(const half8*)&hsh[1][kc * 64 + lane], wB[kc], b0, 0, 0, 0);
        b1 = __builtin_amdgcn_mfma_f32_16x16x32_f16(
            *(const half8*)&hsh[1][(kc + 1) * 64 + lane], wB[kc + 1], b1, 0, 0,
            0);
      }
      half4 xcb_nx = *(const half4*)(xcb_p + pn);
#pragma unroll
      for (int i = 0; i < 4; ++i) {
        float cv = tanh_f(b0[i] + b1[i] + (float)xcb[i]);
        float zz = z_lds[q * 4 + i][16 * wave + ln15];
        float hn = hreg[i] + zz * (cv - hreg[i]);
        _Float16 hh = (_Float16)hn;
        hreg[i] = (float)hh;
        unsigned hb = (unsigned)__builtin_bit_cast(unsigned short, hh);
        st_dw_t<SC1>(h2wr + i * 512, tokhi1 | hb);
        out[((size_t)(q * 4 + i) * S_LEN + t) * 512 + colA] = hn;
      }
      xcb = xcb_nx;
    }
  }
}

// ---- serial recurrence: election + probe + scan ----
__global__ __launch_bounds__(TPB, 1) void rec_kernel(
    const _Float16* __restrict__ Whpk, const _Float16* __restrict__ xgt,
    unsigned* __restrict__ h2, unsigned* __restrict__ rh2,
    unsigned* __restrict__ cnt, float* __restrict__ out) {
  __shared__ int4v hsh[2][1024];  // 32 KB double-buffered fragment stage
  __shared__ float z_lds[16][36];
  __shared__ int s_j, s_fast;

  const int tid = threadIdx.x;
  const int wave = tid >> 6, lane = tid & 63;
  const int bid = blockIdx.x;

  // publish my XCC id (unconditional, LLC-coherent)
  if (tid == 0) {
    unsigned x;
    asm volatile("s_getreg_b32 %0, hwreg(HW_REG_XCC_ID)" : "=s"(x));
    st_dw_t<1>(cnt + bid, 0x100u | (x & 7u));
  }
  if (wave == 0) {
    // wait for all 128 ids (each slot written unconditionally => terminates)
    unsigned a, b;
    for (;;) {
      a = ld_dw_t<1>(cnt + lane);
      b = ld_dw_t<1>(cnt + 64 + lane);
      if (__all((int)((a != 0u) && (b != 0u)))) break;
      __builtin_amdgcn_s_sleep(2);
    }
    unsigned xa = a & 7u, xb = b & 7u;
    int win = 0;
    for (int x = 0; x < 8; ++x) {
      int c = __popcll(__ballot(xa == (unsigned)x)) +
              __popcll(__ballot(xb == (unsigned)x));
      if (c >= NBLK) { win = x; break; }  // pigeonhole: exists
    }
    unsigned myx = (bid < 64) ? __shfl(xa, bid) : __shfl(xb, bid - 64);
    int rank = __popcll(__ballot(xa == (unsigned)win && lane < bid)) +
               __popcll(__ballot(xb == (unsigned)win && (64 + lane) < bid));
    int isw = (myx == (unsigned)win && rank < NBLK) ? 1 : 0;
    int fast = 0;
    if (isw) {
      // bounded sc0-only ping-pong probe on ONE word: 4 rounds, writers 0..3.
      // Same-address updates are only observable when sharing a physical L2.
      int ok = 1;
      for (int r = 0; r < 4 && ok; ++r) {
        if (rank == r && lane == 0) st_dw_t<0>(cnt + 192, 1000u + (unsigned)r);
        unsigned v = 0;
        for (int it = 0; it < 1000; ++it) {
          v = ld_dw_t<0>(cnt + 192);
          if (v == 1000u + (unsigned)r) break;
          __builtin_amdgcn_s_sleep(1);
        }
        if (!__all((int)(v == 1000u + (unsigned)r))) ok = 0;
      }
      if (lane == 0) st_dw_t<1>(cnt + 160 + rank, ok ? 2u : 1u);
      // consensus (LLC-coherent; every candidate publishes => terminates)
      unsigned rv;
      for (;;) {
        rv = (lane < NBLK) ? ld_dw_t<1>(cnt + 160 + lane) : 2u;
        if (__all((int)(rv != 0u))) break;
        __builtin_amdgcn_s_sleep(2);
      }
      fast = __all((int)(rv == 2u)) ? 1 : 0;
    }
    if (lane == 0) {
      s_j = isw ? rank : -1;
      s_fast = fast;
    }
  }
  __syncthreads();
  const int j = s_j;
  if (j < 0) return;

  if (s_fast)
    scan_loop<0>(j, wave, lane, Whpk, xgt, h2, rh2, out, hsh, z_lds);
  else
    scan_loop<1>(j, wave, lane, Whpk, xgt, h2, rh2, out, hsh, z_lds);
}

__global__ void ln_kernel(float* __restrict__ out, const float* __restrict__ gamma,
                          const float* __restrict__ beta) {
  int gw = (blockIdx.x * blockDim.x + threadIdx.x) >> 6;
  int lane = threadIdx.x & 63;
  int nw = (gridDim.x * blockDim.x) >> 6;
  float4 ga = ((const float4*)(gamma + lane * 8))[0];
  float4 gb = ((const float4*)(gamma + lane * 8))[1];
  float4 ba = ((const float4*)(beta + lane * 8))[0];
  float4 bb = ((const float4*)(beta + lane * 8))[1];
  for (int r = gw; r < 16 * S_LEN; r += nw) {
    float* p = out + (size_t)r * 512 + lane * 8;
    float4 v0 = ((float4*)p)[0], v1 = ((float4*)p)[1];
    float s = v0.x + v0.y + v0.z + v0.w + v1.x + v1.y + v1.z + v1.w;
    float sq = v0.x * v0.x + v0.y * v0.y + v0.z * v0.z + v0.w * v0.w +
               v1.x * v1.x + v1.y * v1.y + v1.z * v1.z + v1.w * v1.w;
#pragma unroll
    for (int off = 32; off > 0; off >>= 1) {
      s += __shfl_xor(s, off);
      sq += __shfl_xor(sq, off);
    }
    float mean = s * (1.f / 512.f);
    float var = sq * (1.f / 512.f) - mean * mean;
    float rstd = rsqrtf(var + 1e-5f);
    v0.x = (v0.x - mean) * rstd * ga.x + ba.x;
    v0.y = (v0.y - mean) * rstd * ga.y + ba.y;
    v0.z = (v0.z - mean) * rstd * ga.z + ba.z;
    v0.w = (v0.w - mean) * rstd * ga.w + ba.w;
    v1.x = (v1.x - mean) * rstd * gb.x + bb.x;
    v1.y = (v1.y - mean) * rstd * gb.y + bb.y;
    v1.z = (v1.z - mean) * rstd * gb.z + bb.z;
    v1.w = (v1.w - mean) * rstd * gb.w + bb.w;
    ((float4*)p)[0] = v0;
    ((float4*)p)[1] = v1;
  }
}

extern "C" void kernel_launch(void* const* d_in, const int* in_sizes, int n_in,
                              void* d_out, int out_size, void* d_ws,
                              size_t ws_size, hipStream_t stream) {
  const float* points = (const float*)d_in[0];
  const float* W_gate = (const float*)d_in[1];
  const float* b_gate = (const float*)d_in[2];
  const float* W_cand = (const float*)d_in[3];
  const float* b_cand = (const float*)d_in[4];
  const float* gamma = (const float*)d_in[5];
  const float* beta = (const float*)d_in[6];
  char* ws = (char*)d_ws;
  _Float16* Whpk = (_Float16*)(ws + OFF_WHPK);
  _Float16* Wxpk = (_Float16*)(ws + OFF_WXPK);
  unsigned* h2 = (unsigned*)(ws + OFF_HBUF);
  unsigned* rh2 = (unsigned*)(ws + OFF_RH);
  unsigned* cnt = (unsigned*)(ws + OFF_CNT);
  _Float16* xgt = (_Float16*)(ws + OFF_XGT);
  float* out = (float*)d_out;

  // zero h2 (token 0 == h_0 = 0) + rh2 + election/probe state
  hipMemsetAsync(ws + OFF_HBUF, 0, 81920, stream);
  pack_kernel<<<768, 256, 0, stream>>>(W_gate, W_cand, Whpk, Wxpk);
  xgemm_kernel<<<S_LEN, TPB, 0, stream>>>(points, b_gate, b_cand, Wxpk, xgt);
  rec_kernel<<<NGRID, TPB, 0, stream>>>(Whpk, xgt, h2, rh2, cnt, out);
  ln_kernel<<<512, 256, 0, stream>>>(out, gamma, beta);
}